// Round 5
// baseline (438.599 us; speedup 1.0000x reference)
//
#include <hip/hip_runtime.h>
#include <hip/hip_bf16.h>
#include <stdint.h>

#define T_STEPS 64
#define B_SZ 8
#define C_DIM 64
#define V_SZ 16000
#define K_DIM 4096   // C*C
#define M_ROWS 512   // T*B
#define BM 128
#define BN 128              // 4 waves x 32 cols, disjoint W
#define BK 32
#define NITER (K_DIM / BK)  // 128
#define NWG ((M_ROWS / BM) * (V_SZ / BN))  // 4 * 125 = 500

typedef __bf16 bf16x8 __attribute__((ext_vector_type(8)));
typedef float f32x4 __attribute__((ext_vector_type(4)));

// ---------------- Kernel 1: sequential ctx recurrence ----------------
__global__ void ctx_kernel(const int* __restrict__ tokens,
                           const float* __restrict__ emb_ctx,
                           const float* __restrict__ beta_mult,
                           const float* __restrict__ beta_power,
                           float* __restrict__ ctx_hist) {
  const int b = blockIdx.x;
  const int d = threadIdx.x;
  const float bm = beta_mult[0];
  const float bp = beta_power[0];
  float ctx = 0.0f;
  for (int t = 0; t < T_STEPS; ++t) {
    const int tok = tokens[t * B_SZ + b];
    const float ce = emb_ctx[tok * C_DIM + d];
    float ne2 = ce * ce;
    float c2 = ctx * ctx;
#pragma unroll
    for (int s = 32; s > 0; s >>= 1) {
      ne2 += __shfl_xor(ne2, s, 64);
      c2 += __shfl_xor(c2, s, 64);
    }
    const float ne = sqrtf(ne2);
    const float nc = sqrtf(c2);
    float beta = powf(bm * (ne / (ne + nc)), bp);  // ALPHA == 1
    beta = fminf(fmaxf(beta, 0.0f), 1.0f);
    ctx = (1.0f - beta) * ctx + beta * ce;
    ctx_hist[(t * B_SZ + b) * C_DIM + d] = ctx;
  }
}

// ---------------- Kernel 2: fused GEMM with on-the-fly A ----------------------
// out[512,16000] = M[512,4096] * W^T, where M[m, c*64+d] = ae[m][c]*ctx[m][d].
// Per BK=32 tile kt: c = kt>>1 is CONSTANT -> A-frags are built in registers
// from ctx (bf16, VGPR-resident) scaled by ae[row][c] (f32 in LDS).
// Block 128M x 128N, 4 waves each 128M x 32N (disjoint W cols -> W read
// exactly once device-wide -> nontemporal safe). W: f32 nt-load depth-4 reg
// ring -> cvt bf16 -> wave-PRIVATE 2-slot LDS -> bv frags. Zero k-loop
// barriers; 2 blocks/CU. Only sync: one __syncthreads after ae_t prologue.
__global__ __launch_bounds__(256, 2)
void gemm_kernel(const int* __restrict__ tokens,
                 const float* __restrict__ emb_act,
                 const float* __restrict__ ctx_hist,
                 const float* __restrict__ W,
                 float* __restrict__ out) {
  __shared__ float ae_t[C_DIM][BM];   // 32 KB, [c][m_local]
  __shared__ char wlds[4][2][2048];   // [wave][slot][g(4)][n_local(32)][16B]

  const int tid = threadIdx.x;
  const int lane = tid & 63;
  const int w = tid >> 6;
  const int lrow = lane & 15;
  const int g = lane >> 4;

  const int bid = blockIdx.x;
  const int mi = bid & 3;
  const int nj = bid >> 2;
  const int m0 = mi * BM;
  const int n0 = nj * BN + w * 32;  // this wave's 32 W-cols

  // ---- prologue A: ae_t[c][m] = emb_act[tokens[m0+m]][c] ----
  {
    const int m = tid & 127;
    const int c0 = (tid >> 7) * 32;
    const int tok = tokens[m0 + m];
    const float* ap = emb_act + (size_t)tok * C_DIM + c0;
#pragma unroll
    for (int i = 0; i < 32; ++i) ae_t[c0 + i][m] = ap[i];
  }

  // ---- prologue: ctx slices -> registers (bf16), rows fm*16+lrow ----
  bf16x8 ctxr[8][2];
#pragma unroll
  for (int fm = 0; fm < 8; ++fm)
#pragma unroll
    for (int h = 0; h < 2; ++h) {
      const float* cp =
          ctx_hist + (size_t)(m0 + fm * 16 + lrow) * C_DIM + h * 32 + g * 8;
      const f32x4 c0 = *(const f32x4*)cp;
      const f32x4 c1 = *(const f32x4*)(cp + 4);
      bf16x8 v;
#pragma unroll
      for (int j = 0; j < 4; ++j) {
        v[j] = (__bf16)c0[j];
        v[4 + j] = (__bf16)c1[j];
      }
      ctxr[fm][h] = v;
    }

  __syncthreads();  // ae_t ready; the ONLY block-wide sync

  // ---- W staging setup: this lane owns row n0+(lane>>1), k-half (lane&1) ----
  const float* const wp =
      W + (size_t)(n0 + (lane >> 1)) * K_DIM + (lane & 1) * 16;
  char* const wbase = &wlds[w][0][0] + (lane >> 1) * 16;
  const int gw = (lane & 1) * 2;  // first g-group this lane writes

  f32x4 ring[4][4];  // [slot = tile&3][quad]; tile tau lives in slot tau&3
#pragma unroll
  for (int s = 0; s < 4; ++s) {
    const float* p = wp + s * BK;
#pragma unroll
    for (int q = 0; q < 4; ++q)
      ring[s][q] = __builtin_nontemporal_load((const f32x4*)(p + q * 4));
  }

  // cvt + ds_write a ring slot into LDS slot `ls`
  auto WSTORE = [&](int rs, int ls) {
    bf16x8 w0, w1;
#pragma unroll
    for (int j = 0; j < 4; ++j) {
      w0[j] = (__bf16)ring[rs][0][j];
      w0[4 + j] = (__bf16)ring[rs][1][j];
      w1[j] = (__bf16)ring[rs][2][j];
      w1[4 + j] = (__bf16)ring[rs][3][j];
    }
    char* d = wbase + ls * 2048;
    *(bf16x8*)(d + gw * 512) = w0;
    *(bf16x8*)(d + (gw + 1) * 512) = w1;
  };

  WSTORE(0, 0);  // tile 0 -> LDS slot 0

  f32x4 acc[8][2];
#pragma unroll
  for (int fm = 0; fm < 8; ++fm)
#pragma unroll
    for (int fn = 0; fn < 2; ++fn) acc[fm][fn] = (f32x4){0.f, 0.f, 0.f, 0.f};

  float aev[8];

#pragma unroll 1
  for (int p = 0; p < NITER / 4; ++p) {
#pragma unroll
    for (int u = 0; u < 4; ++u) {
      const int kt = p * 4 + u;
      // 1. load tile kt+4 -> ring slot kt&3 (freed: tile kt cvt'd at iter kt-1)
      {
        const int ktl = (kt + 4 < NITER) ? kt + 4 : NITER - 1;
        const float* pp = wp + (size_t)ktl * BK;
#pragma unroll
        for (int q = 0; q < 4; ++q)
          ring[u][q] = __builtin_nontemporal_load((const f32x4*)(pp + q * 4));
      }
      // 2. cvt + write tile kt+1 (loaded 3 iters ago) -> LDS slot (kt+1)&1
      WSTORE((u + 1) & 3, (kt + 1) & 1);
      // 3. ae scalars (c = kt>>1 changes on even kt)
      if ((u & 1) == 0) {
#pragma unroll
        for (int fm = 0; fm < 8; ++fm) aev[fm] = ae_t[kt >> 1][fm * 16 + lrow];
      }
      // 4. bv frags from LDS slot kt&1
      const char* rb = &wlds[w][kt & 1][0];
      const bf16x8 bv0 = *(const bf16x8*)(rb + g * 512 + lrow * 16);
      const bf16x8 bv1 = *(const bf16x8*)(rb + g * 512 + (16 + lrow) * 16);
      // 5. build A-frags in regs and MFMA
      const int half = kt & 1;
#pragma unroll
      for (int fm = 0; fm < 8; ++fm) {
        const float av = aev[fm];
        const bf16x8 cx = ctxr[fm][half];
        bf16x8 af;
#pragma unroll
        for (int j = 0; j < 8; ++j) af[j] = (__bf16)(av * (float)cx[j]);
        acc[fm][0] =
            __builtin_amdgcn_mfma_f32_16x16x32_bf16(af, bv0, acc[fm][0], 0, 0, 0);
        acc[fm][1] =
            __builtin_amdgcn_mfma_f32_16x16x32_bf16(af, bv1, acc[fm][1], 0, 0, 0);
      }
    }
  }

  // ---- epilogue: C/D layout col = lane&15, row = (lane>>4)*4 + q ----
#pragma unroll
  for (int fm = 0; fm < 8; ++fm)
#pragma unroll
    for (int q = 0; q < 4; ++q) {
      const int row = m0 + fm * 16 + g * 4 + q;
      float* po = out + (size_t)row * V_SZ + n0 + lrow;
#pragma unroll
      for (int fn = 0; fn < 2; ++fn) po[fn * 16] = acc[fm][fn][q];
    }
}

extern "C" void kernel_launch(void* const* d_in, const int* in_sizes, int n_in,
                              void* d_out, int out_size, void* d_ws, size_t ws_size,
                              hipStream_t stream) {
  const int* tokens = (const int*)d_in[0];
  const float* emb_ctx = (const float*)d_in[1];
  const float* emb_act = (const float*)d_in[2];
  const float* W = (const float*)d_in[3];
  const float* beta_mult = (const float*)d_in[4];
  const float* beta_power = (const float*)d_in[5];
  float* out = (float*)d_out;

  float* ctx_hist = (float*)d_ws;  // 512*64*4 = 128 KB

  ctx_kernel<<<B_SZ, C_DIM, 0, stream>>>(tokens, emb_ctx, beta_mult, beta_power,
                                         ctx_hist);
  gemm_kernel<<<NWG, 256, 0, stream>>>(tokens, emb_act, ctx_hist, W, out);
}

// Round 6
// 193.558 us; speedup vs baseline: 2.2660x; 2.2660x over previous
//
#include <hip/hip_runtime.h>
#include <hip/hip_bf16.h>
#include <stdint.h>

#define T_STEPS 64
#define B_SZ 8
#define C_DIM 64
#define V_SZ 16000
#define K_DIM 4096   // C*C
#define M_ROWS 512   // T*B
#define BM 128
#define BN 128
#define BK 32
#define NITER (K_DIM / BK)  // 128
#define NWG ((M_ROWS / BM) * (V_SZ / BN))  // 500
#define ABYTES 8192          // 128 x 32 bf16, LDS layout [g][r128][16B]
#define WBYTES 16384         // 128 x 32 f32, LDS layout [n128][k 128B] ^ ((n&7)<<4)
#define BUFBYTES (ABYTES + WBYTES)  // 24576

typedef __bf16 bf16x8 __attribute__((ext_vector_type(8)));
typedef float f32x4 __attribute__((ext_vector_type(4)));

__device__ __forceinline__ void gll16(const void* g, void* l) {
  __builtin_amdgcn_global_load_lds(
      (const __attribute__((address_space(1))) void*)g,
      (__attribute__((address_space(3))) void*)l, 16, 0, 0);
}

// ---------------- Kernel 1: sequential ctx recurrence ----------------
__global__ void ctx_kernel(const int* __restrict__ tokens,
                           const float* __restrict__ emb_ctx,
                           const float* __restrict__ beta_mult,
                           const float* __restrict__ beta_power,
                           float* __restrict__ ctx_hist) {
  const int b = blockIdx.x;
  const int d = threadIdx.x;
  const float bm = beta_mult[0];
  const float bp = beta_power[0];
  float ctx = 0.0f;
  for (int t = 0; t < T_STEPS; ++t) {
    const int tok = tokens[t * B_SZ + b];
    const float ce = emb_ctx[tok * C_DIM + d];
    float ne2 = ce * ce;
    float c2 = ctx * ctx;
#pragma unroll
    for (int s = 32; s > 0; s >>= 1) {
      ne2 += __shfl_xor(ne2, s, 64);
      c2 += __shfl_xor(c2, s, 64);
    }
    const float ne = sqrtf(ne2);
    const float nc = sqrtf(c2);
    float beta = powf(bm * (ne / (ne + nc)), bp);  // ALPHA == 1
    beta = fminf(fmaxf(beta, 0.0f), 1.0f);
    ctx = (1.0f - beta) * ctx + beta * ce;
    ctx_hist[(t * B_SZ + b) * C_DIM + d] = ctx;
  }
}

// ---------------- Kernel 2: build M in MFMA-fragment-blocked layout ----------
// (m,k) -> byte (k>>5)*32768 + ((k>>3)&3)*8192 + m*16 + (k&7)*2.
// Tile kt = contiguous 32KB; within it, [g][m512][16B] — gll16 sources are
// fully contiguous 2KB runs.
__global__ void build_m(const int* __restrict__ tokens,
                        const float* __restrict__ emb_act,
                        const float* __restrict__ ctx_hist,
                        char* __restrict__ Mblk) {
  const int m = blockIdx.x;
  const int tid = threadIdx.x;
  __shared__ float ctxs[C_DIM];
  __shared__ float aes[C_DIM];
  const int t = m >> 3, b = m & 7;
  const int tok = tokens[t * B_SZ + b];
  if (tid < C_DIM) {
    ctxs[tid] = ctx_hist[m * C_DIM + tid];
    aes[tid] = emb_act[tok * C_DIM + tid];
  }
  __syncthreads();
  const int c = tid >> 1;
  const int dh = (tid & 1) * 32;
  const float ae = aes[c];
#pragma unroll
  for (int q = 0; q < 4; ++q) {
    const int k0 = c * C_DIM + dh + q * 8;
    bf16x8 v;
#pragma unroll
    for (int jj = 0; jj < 8; ++jj) v[jj] = (__bf16)(ae * ctxs[dh + q * 8 + jj]);
    *(bf16x8*)(void*)(Mblk + (size_t)(k0 >> 5) * 32768 + ((k0 >> 3) & 3) * 8192 +
                      m * 16) = v;
  }
}

// ---------------- Kernel 3: GEMM out[512,16000] = M[512,4096] * W^T ------------
// 128x128 tile, 4 waves (2x2, 64x64 each), grid 500 -> 2 blocks/CU.
// 3-buffer LDS (72KB), depth-2 prefetch, counted vmcnt(12), 2 barriers/iter,
// never vmcnt(0) in the loop (T3+T4). All staging via gll16 (6 issues/wave/
// tile). A: blocked-M, contiguous sources, conflict-free LDS. W: f32 with
// read-side XOR swizzle ^((col&7)<<4), inverse applied to the global source
// (rule #21); frags cvt'd to bf16 at use. XCD swizzle (m204 bijective,
// q=62 r=4) makes the 4 blocks sharing a W panel XCD-siblings.
__global__ __launch_bounds__(256, 2)
void gemm_kernel(const char* __restrict__ Ablk, const float* __restrict__ W,
                 float* __restrict__ out) {
  __shared__ __align__(16) char smem[3][BUFBYTES];
  const int tid = threadIdx.x;
  const int lane = tid & 63;
  const int w = tid >> 6;
  const int wm = w >> 1, wn = w & 1;
  const int lrow = lane & 15;
  const int g = lane >> 4;

  const int orig = blockIdx.x;
  const int xcd = orig & 7;
  const int wg = ((xcd < 4) ? xcd * 63 : 252 + (xcd - 4) * 62) + (orig >> 3);
  const int m0 = (wg & 3) * BM;
  const int n0 = (wg >> 2) * BN;

  // Staging sources (per-thread, advanced by kt at issue time).
  const char* const abase =
      Ablk + (tid >> 7) * 8192 + (size_t)(m0 + (tid & 127)) * 16;
  const char* const Wc = (const char*)W;
  const int woff = ((tid & 7) * 16) ^ (((tid >> 3) & 7) << 4);  // pre-swizzle
  const char* wbase[4];
#pragma unroll
  for (int s = 0; s < 4; ++s)
    wbase[s] = Wc + (size_t)(n0 + s * 32 + (tid >> 3)) * (K_DIM * 4) + woff;

  auto STAGE = [&](int b, int kt) {
    char* dst = smem[b];
#pragma unroll
    for (int s = 0; s < 2; ++s)
      gll16(abase + (size_t)kt * 32768 + s * 16384, dst + s * 4096 + tid * 16);
#pragma unroll
    for (int s = 0; s < 4; ++s)
      gll16(wbase[s] + (size_t)kt * 128, dst + ABYTES + s * 4096 + tid * 16);
  };

  f32x4 acc[4][4];
#pragma unroll
  for (int fm = 0; fm < 4; ++fm)
#pragma unroll
    for (int fn = 0; fn < 4; ++fn) acc[fm][fn] = (f32x4){0.f, 0.f, 0.f, 0.f};

  auto COMPUTE = [&](int b) {
    const char* Ab = smem[b];
    const char* Wb = smem[b] + ABYTES;
    bf16x8 a[4];
#pragma unroll
    for (int fm = 0; fm < 4; ++fm)
      a[fm] = *(const bf16x8*)(Ab + g * 2048 + (wm * 64 + fm * 16 + lrow) * 16);
#pragma unroll
    for (int fn = 0; fn < 4; ++fn) {
      const int col = wn * 64 + fn * 16 + lrow;
      const int xo = (col & 7) << 4;
      const f32x4 b0 = *(const f32x4*)(Wb + col * 128 + ((g * 32) ^ xo));
      const f32x4 b1 = *(const f32x4*)(Wb + col * 128 + ((g * 32 + 16) ^ xo));
      bf16x8 bv;
#pragma unroll
      for (int j = 0; j < 4; ++j) {
        bv[j] = (__bf16)b0[j];
        bv[4 + j] = (__bf16)b1[j];
      }
#pragma unroll
      for (int fm = 0; fm < 4; ++fm)
        acc[fm][fn] =
            __builtin_amdgcn_mfma_f32_16x16x32_bf16(a[fm], bv, acc[fm][fn], 0, 0, 0);
    }
  };

  STAGE(0, 0);
  STAGE(1, 1);

  int cur = 0;
#pragma unroll 1
  for (int kt = 0; kt < NITER - 2; ++kt) {
    const int stg = (cur == 0) ? 2 : cur - 1;  // (cur+2)%3, freed 2 iters ago
    STAGE(stg, kt + 2);
    asm volatile("s_waitcnt vmcnt(12)" ::: "memory");  // tile kt's 6 landed
    __builtin_amdgcn_s_barrier();
    COMPUTE(cur);
    __builtin_amdgcn_s_barrier();  // all frag reads done before buf reuse
    cur = (cur == 2) ? 0 : cur + 1;
  }
  asm volatile("s_waitcnt vmcnt(6)" ::: "memory");
  __builtin_amdgcn_s_barrier();
  COMPUTE(cur);
  __builtin_amdgcn_s_barrier();
  cur = (cur == 2) ? 0 : cur + 1;
  asm volatile("s_waitcnt vmcnt(0)" ::: "memory");
  __builtin_amdgcn_s_barrier();
  COMPUTE(cur);

  // Epilogue: C/D layout col = lane&15, row = (lane>>4)*4 + q.
#pragma unroll
  for (int fm = 0; fm < 4; ++fm)
#pragma unroll
    for (int q = 0; q < 4; ++q) {
      const int row = m0 + wm * 64 + fm * 16 + g * 4 + q;
      float* po = out + (size_t)row * V_SZ + n0 + wn * 64 + lrow;
#pragma unroll
      for (int fn = 0; fn < 4; ++fn) po[fn * 16] = acc[fm][fn][q];
    }
}

extern "C" void kernel_launch(void* const* d_in, const int* in_sizes, int n_in,
                              void* d_out, int out_size, void* d_ws, size_t ws_size,
                              hipStream_t stream) {
  const int* tokens = (const int*)d_in[0];
  const float* emb_ctx = (const float*)d_in[1];
  const float* emb_act = (const float*)d_in[2];
  const float* W = (const float*)d_in[3];
  const float* beta_mult = (const float*)d_in[4];
  const float* beta_power = (const float*)d_in[5];
  float* out = (float*)d_out;

  char* Mblk = (char*)d_ws;  // 4 MB, blocked layout
  float* ctx_hist = (float*)((char*)d_ws + (size_t)M_ROWS * K_DIM * 2);  // 128 KB

  ctx_kernel<<<B_SZ, C_DIM, 0, stream>>>(tokens, emb_ctx, beta_mult, beta_power,
                                         ctx_hist);
  build_m<<<M_ROWS, 128, 0, stream>>>(tokens, emb_act, ctx_hist, Mblk);
  gemm_kernel<<<NWG, 256, 0, stream>>>(Mblk, W, out);
}